// Round 14
// baseline (660.298 us; speedup 1.0000x reference)
//
#include <hip/hip_runtime.h>

#define HID 128
#define CELLS 98304
#define NE 250000
#define NSTEPS 2
#define NWIN 3912  // 64-edge windows per edge type = 489 blocks * 8 waves

typedef __attribute__((ext_vector_type(8))) short short8;
typedef __attribute__((ext_vector_type(4))) float f32x4;
typedef __attribute__((ext_vector_type(4))) unsigned int u32x4;
typedef unsigned short u16;

// pi permutation: pi-slot s <-> natural col permf(s)
__device__ __forceinline__ int permf(int s) { return ((s & 7) << 4) | (s >> 3); }
// m storage position p: half = p>>6, lane = p&63,
// pi-slot = (lane>>2)*8 + half*4 + (lane&3); natural col = permf(slot)
__device__ __forceinline__ int nat_of_pos(int p) {
  int l = p & 63, hf = p >> 6;
  int slot = ((l >> 2) << 3) + (hf << 2) + (l & 3);
  return ((slot & 7) << 4) | (slot >> 3);
}

__device__ __forceinline__ u16 f2bf(float f) {
  unsigned int u = __builtin_bit_cast(unsigned int, f);
  u += 0x7fffu + ((u >> 16) & 1u);
  return (u16)(u >> 16);
}
__device__ __forceinline__ float bf2f(u16 s) {
  unsigned int u = ((unsigned int)s) << 16;
  return __builtin_bit_cast(float, u);
}
// packed f32x2 -> bf16x2 (RNE), lo -> D[15:0], hi -> D[31:16]
__device__ __forceinline__ unsigned int cvtpk_bf16(float lo, float hi) {
  unsigned int r;
  asm("v_cvt_pk_bf16_f32 %0, %1, %2" : "=v"(r) : "v"(lo), "v"(hi));
  return r;
}
__device__ __forceinline__ float sigm(float x) { return 1.f / (1.f + __expf(-x)); }
__device__ __forceinline__ float tanha(float x) { return 1.f - 2.f / (__expf(2.f * x) + 1.f); }

// zero-register DMA: 16B per lane, global(per-lane addr) -> LDS (wave-uniform base + lane*16)
__device__ __forceinline__ void gload_lds16(const u16* g, u16* l) {
  __builtin_amdgcn_global_load_lds(
      (const __attribute__((address_space(1))) unsigned int*)(const void*)g,
      (__attribute__((address_space(3))) unsigned int*)(void*)l, 16, 0, 0);
}

// cooperative 16KB weight-chunk stage (msg): 512 threads x 2 insts x 16B, linear
__device__ __forceinline__ void stage_w(const u16* __restrict__ ws, u16* wl, int w, int lane) {
  #pragma unroll
  for (int i = 0; i < 2; ++i)
    gload_lds16(ws + i * 4096 + w * 512 + lane * 8, wl + i * 4096 + w * 512);
}

// ---------------- prep: bf16-convert weights ----------------
// W0b: [et][chunk t=0..3][n=128][s=64] -- K-chunks of 64, XOR-swizzled within chunk:
//   position group g' (0..7) of row n holds natural k-group g'^(n&7) of chunk t.
//   t=0,1: src half (k 0..127), t=2,3: dst half (k 128..255). Natural K (h order).
// W123b: [l-1][et][half hh][n][s=64], same per-chunk swizzle, K pi-permuted (tile order).
// Wcb2: [kc=0..7][n=0..511][g'=0..7][j=0..7] -- lstm gates weights in K-chunks of
//   64, XOR-swizzled within chunk; K = [Wih(x | m0 | m1) | Whh], m-blocks m-storage order.
__global__ void prep_kernel(
    const float* __restrict__ W0, const float* __restrict__ W1,
    const float* __restrict__ W2, const float* __restrict__ W3,
    const float* __restrict__ b0, const float* __restrict__ b1,
    const float* __restrict__ b2, const float* __restrict__ b3,
    const float* __restrict__ Wih, const float* __restrict__ Whh,
    const float* __restrict__ sw,
    u16* __restrict__ W0b, u16* __restrict__ W123b,
    u16* __restrict__ Wcb, float* __restrict__ bp, float* __restrict__ swp)
{
  int idx = blockIdx.x * 256 + threadIdx.x;
  if (idx < 65536) {  // W0b swizzled chunks
    int et = idx >> 15, t = (idx >> 13) & 3, n = (idx >> 6) & 127, s = idx & 63;
    int g = s >> 3, j = s & 7;
    int gn = g ^ (n & 7);
    W0b[idx] = f2bf(W0[(et * 128 + n) * 256 + t * 64 + gn * 8 + j]);
    return;
  }
  idx -= 65536;
  if (idx < 98304) {  // W123b swizzled half-chunks, K pi-permuted
    int which = idx >> 15, r = idx & 32767;
    int et = r >> 14, hh = (r >> 13) & 1, n = (r >> 6) & 127, s = r & 63;
    int g = s >> 3, j = s & 7;
    int gn = g ^ (n & 7);
    const float* W = which == 0 ? W1 : (which == 1 ? W2 : W3);
    W123b[which * 32768 + r] = f2bf(W[(et * 128 + n) * 128 + permf(hh * 64 + gn * 8 + j)]);
    return;
  }
  idx -= 98304;
  if (idx < 262144) {  // Wcb2 chunk-swizzled lstm weights
    int kc = idx >> 15, r = idx & 32767;
    int n = r >> 6, s = r & 63;
    int gp = s >> 3, j = s & 7;
    int k = kc * 64 + ((gp ^ (n & 7)) << 3) + j;   // natural concat-K position
    int blk = k >> 7, s7 = k & 127;
    int k7 = (blk == 1 || blk == 2) ? nat_of_pos(s7) : s7;  // x / rh natural
    float v = (blk < 3) ? Wih[n * 384 + blk * 128 + k7] : Whh[n * 128 + k7];
    Wcb[idx] = f2bf(v);
    return;
  }
  idx -= 262144;
  if (idx < 1024) {  // biases [layer 0..3][et][slot] pi-order
    int l = idx >> 8, r = idx & 255;
    int et = r >> 7, s = r & 127;
    const float* b = l == 0 ? b0 : (l == 1 ? b1 : (l == 2 ? b2 : b3));
    bp[idx] = b[et * 128 + permf(s)];
    return;
  }
  idx -= 1024;
  if (idx < 128) swp[idx] = sw[idx];
}

// ---------------- init: x = embed[q] (natural, bf16), h = x (rc untouched:
// step 0 never reads it). Reads the 1.5KB f32 embed table directly (L1-resident).
__global__ void init_kernel(const int* __restrict__ q, const float* __restrict__ embed,
                            u16* __restrict__ xb, u16* __restrict__ h)
{
  int idx = blockIdx.x * 256 + threadIdx.x;
  int c = idx >> 7, s = idx & 127;
  u16 v = f2bf(embed[q[c] * 128 + s]);
  xb[idx] = v;
  h[idx] = v;
}

// ---------------- dst-sort pipeline: hist -> scan (2 kernels) -> scatter ----------------
__global__ void hist_kernel(const int* __restrict__ edst, int* __restrict__ counts)
{
  int idx = blockIdx.x * 256 + threadIdx.x;
  if (idx >= 2 * NE) return;
  int et = (idx >= NE) ? 1 : 0;
  atomicAdd(&counts[et * CELLS + edst[idx]], 1);
}

// R13: wave-level shfl scan (1 barrier) instead of 20-barrier Hillis-Steele.
__global__ void scan1_kernel(const int* __restrict__ counts, int* __restrict__ S,
                             int* __restrict__ btot)
{
  __shared__ int wsum[16];
  const int t = threadIdx.x, b = blockIdx.x;
  const int lane = t & 63, wv = t >> 6;
  const int i = b * 1024 + t;
  const int v = counts[i];
  // inclusive wave scan
  int acc = v;
  #pragma unroll
  for (int off = 1; off < 64; off <<= 1) {
    int n = __shfl_up(acc, off);
    if (lane >= off) acc += n;
  }
  if (lane == 63) wsum[wv] = acc;
  __syncthreads();
  int wpref = 0;
  for (int j = 0; j < wv; ++j) wpref += wsum[j];  // <=15 LDS broadcasts
  acc += wpref;
  S[i] = acc - v;  // block-local exclusive
  if (t == 1023) btot[b] = acc;
}

// R13: fused scan2+scan3 -- each block tree-reduces its own prefix of btot.
__global__ void scan23_kernel(const int* __restrict__ btot, int* __restrict__ S)
{
  __shared__ int sh[256];
  const int t = threadIdx.x, b = blockIdx.x;
  if (t < 256) sh[t] = (t < b) ? btot[t] : 0;  // b <= 191 < 256
  __syncthreads();
  #pragma unroll
  for (int off = 128; off > 0; off >>= 1) {
    if (t < off) sh[t] += sh[t + off];
    __syncthreads();
  }
  const int boff = sh[0];
  S[b * 1024 + t] += boff;
  if (b == 0 && t == 0) S[2 * CELLS] = 2 * NE;
}

// R14: packed (src,dst) pair -- ONE 8B scattered store per edge instead of two 4B
// (halves scattered-write transactions; msg's prologue gathers become single 8B loads).
__global__ void scatter_kernel(const int* __restrict__ esrc, const int* __restrict__ edst,
                               const int* __restrict__ S, int* __restrict__ fill,
                               int2* __restrict__ sp)
{
  int idx = blockIdx.x * 256 + threadIdx.x;
  if (idx >= 2 * NE) return;
  int et = (idx >= NE) ? 1 : 0;
  int d = edst[idx];
  int pos = atomicAdd(&fill[et * CELLS + d], 1);
  int slot = S[et * CELLS + d] - et * NE + pos;  // et-local sorted slot
  int2 v;
  v.x = esrc[idx];
  v.y = d;
  sp[et * NE + slot] = v;
}

// bias + relu + pack-transpose into swizzled per-wave LDS A-tile (pitch 128, 8-col XOR
// swizzle). Packed conversion via cvt_pk (R6).
__device__ __forceinline__ void bias_relu_store(f32x4 (&acc)[4][8], const float* __restrict__ bl,
                                                u16* __restrict__ ab, int q, int c)
{
  float bias[8];
  #pragma unroll
  for (int j = 0; j < 8; ++j) bias[j] = bl[c * 8 + j];
  #pragma unroll
  for (int mt = 0; mt < 4; ++mt) {
    #pragma unroll
    for (int r = 0; r < 4; ++r) {
      const int rowl = mt * 16 + 4 * q + r;
      u32x4 t;
      #pragma unroll
      for (int p = 0; p < 4; ++p) {
        float v0 = acc[mt][2 * p][r] + bias[2 * p];
        float v1 = acc[mt][2 * p + 1][r] + bias[2 * p + 1];
        v0 = v0 > 0.f ? v0 : 0.f;
        v1 = v1 > 0.f ? v1 : 0.f;
        t[p] = cvtpk_bf16(v0, v1);
      }
      *(u32x4*)(ab + rowl * 128 + ((c ^ (rowl & 15)) << 3)) = t;
    }
  }
}

// ---------------- fused 4-layer edge MLP + sorted segmented-sum scatter ----------------
// Parked at the measured-best R6 config (8-wave blocks, 64-edge windows, 10-chunk
// 2-deep wbuf pipeline, cvt_pk packing). R14: prologue reads the packed sp[] pairs
// (one 8B load per edge slot instead of separate src/dst 4B gathers). Body unchanged.
__launch_bounds__(512, 2)
__global__ void msg_kernel(
    const u16* __restrict__ h,
    const int2* __restrict__ sp, const int* __restrict__ S,
    const u16* __restrict__ W0b, const u16* __restrict__ W123b,
    const float* __restrict__ bp,
    u16* __restrict__ m0, u16* __restrict__ m1,
    int* __restrict__ side_dst, float* __restrict__ side_part)
{
  __shared__ u16 abuf[8][64 * 128];   // 128KB: wave-private A-tiles, XOR-swizzled
  __shared__ u16 wbuf[2][128 * 64];   // 32KB: double-buffered weight chunk [n=128][k=64]
  const int et = blockIdx.y;
  const int tid = threadIdx.x;
  const int w = tid >> 6, lane = tid & 63, q = lane >> 4, c = lane & 15;
  const int ebase = blockIdx.x * 512 + w * 64;  // et-local sorted slot base for this wave
  const int win = blockIdx.x * 8 + w;
  const int2* __restrict__ sp2 = sp + et * NE;
  u16* __restrict__ msgs = (et == 0) ? m0 : m1;
  u16* ab = abuf[w];

  // per-lane edge pair (src,dst) in one 8B load; srow for DMA, dval for run masks
  int eS = ebase + lane;
  if (eS >= NE) eS = NE - 1;
  const int2 pe = sp2[eS];
  const int srow = pe.x;

  int rowD[4];
  #pragma unroll
  for (int mt = 0; mt < 4; ++mt) {
    int e = ebase + mt * 16 + c;
    if (e >= NE) e = NE - 1;
    rowD[mt] = sp2[e].y;
  }

  // issue 16 zero-register DMA gathers: h[src] rows -> own swizzled LDS tile.
  // position (row r, group cg) holds natural group cg ^ (r&15).
  #pragma unroll
  for (int i = 0; i < 16; ++i) {
    const int r = i * 4 + (lane >> 4);
    const int grow = __shfl(srow, r);
    const int cg = lane & 15;
    gload_lds16(h + (size_t)grow * 128 + ((cg ^ (r & 15)) << 3), ab + i * 512);
  }
  // chunk 0 (W0 t=2) into wbuf[0]; nobody reads wbuf before the prologue barrier
  stage_w(W0b + (et * 4 + 2) * 8192, wbuf[0], w, lane);

  // run structure (wave-uniform masks). Cross-lane ops unconditional.
  const int eL = ebase + lane;
  const int dval = (eL < NE) ? pe.y : -1;
  int rpS = 0, rpE = 0;
  if (dval >= 0) {
    rpS = S[et * CELLS + dval] - et * NE;
    rpE = S[et * CELLS + dval + 1] - et * NE;
  }
  const int dlagged = __shfl_up(dval, 1);          // all 64 lanes active
  const bool headp = (lane == 0) | (dval != dlagged);
  const unsigned long long tails = (__ballot(headp) >> 1) | (1ull << 63);
  const unsigned long long intmask = __ballot(dval >= 0 && rpS >= ebase && rpE <= ebase + 64);

  const f32x4 zf = {0.f, 0.f, 0.f, 0.f};
  f32x4 acc[4][8];
  #pragma unroll
  for (int mt = 0; mt < 4; ++mt)
    #pragma unroll
    for (int nt = 0; nt < 8; ++nt) acc[mt][nt] = zf;

  asm volatile("s_waitcnt vmcnt(0)" ::: "memory");  // A-DMAs + chunk 0 landed
  __syncthreads();

  // ---- 10-chunk pipelined K-loop ----
  #pragma unroll 1
  for (int i = 0; i < 10; ++i) {
    // stage next chunk into the buffer whose readers finished at the previous barrier
    if (i < 9) {
      const int j = i + 1;
      const u16* wsrc;
      if (j < 4) {
        const int t = (j < 2) ? (j + 2) : (j - 2);
        wsrc = W0b + (et * 4 + t) * 8192;
      } else {
        const int li = j - 4;  // (l-1)*2 + hh
        wsrc = W123b + (li >> 1) * 32768 + et * 16384 + (li & 1) * 8192;
      }
      stage_w(wsrc, wbuf[j & 1], w, lane);
    }
    // at the start of each layer chunk-pair: flush previous layer into own A-tile
    if (i >= 4 && !(i & 1)) {
      bias_relu_store(acc, bp + ((i - 4) >> 1) * 256 + et * 128, ab, q, c);
      #pragma unroll
      for (int mt = 0; mt < 4; ++mt)
        #pragma unroll
        for (int nt = 0; nt < 8; ++nt) acc[mt][nt] = zf;
    }
    const u16* wb = wbuf[i & 1];
    #pragma unroll
    for (int ks = 0; ks < 2; ++ks) {
      short8 a[4], b[8];
      if (i < 2) {  // dst half of L0: register gathers (sorted runs -> cache hits)
        const int kqh = i * 64 + ks * 32 + q * 8;
        #pragma unroll
        for (int mt = 0; mt < 4; ++mt)
          a[mt] = *(const short8*)(h + (size_t)rowD[mt] * HID + kqh);
      } else {      // src half of L0 / layers 1-3: own swizzled A-tile
        const int blk = (i & 1) * 8 + ks * 4 + q;
        #pragma unroll
        for (int mt = 0; mt < 4; ++mt) {
          const int row = mt * 16 + c;
          a[mt] = *(const short8*)(ab + row * 128 + ((blk ^ c) << 3));
        }
      }
      #pragma unroll
      for (int nt = 0; nt < 8; ++nt)
        b[nt] = *(const short8*)(wb + (nt * 16 + c) * 64 + (((ks * 4 + q) ^ (c & 7)) << 3));
      #pragma unroll
      for (int mt = 0; mt < 4; ++mt)
        #pragma unroll
        for (int nt = 0; nt < 8; ++nt)
          acc[mt][nt] = __builtin_amdgcn_mfma_f32_16x16x32_bf16(a[mt], b[nt], acc[mt][nt], 0, 0, 0);
    }
    // next chunk's DMA latency was covered by this compute; pay only the residual
    asm volatile("s_waitcnt vmcnt(0)" ::: "memory");
    __syncthreads();
  }

  // layer-3 epilogue: +bias into fp32 fab (two 64-feature passes), column scan; interior
  // flush = 128B coalesced bf16 store; boundary flush = fp32 partial to side buffer.
  float bias[8];
  #pragma unroll
  for (int j = 0; j < 8; ++j) bias[j] = bp[3 * 256 + et * 128 + c * 8 + j];

  float* fab = (float*)ab;  // 64 rows x 64 feature-slots fp32 (16KB, wave-private)
  #pragma unroll
  for (int half = 0; half < 2; ++half) {
    #pragma unroll
    for (int mt = 0; mt < 4; ++mt) {
      #pragma unroll
      for (int r = 0; r < 4; ++r) {
        const int row = mt * 16 + 4 * q + r;
        f32x4 t;
        #pragma unroll
        for (int nti = 0; nti < 4; ++nti)
          t[nti] = acc[mt][half * 4 + nti][r] + bias[half * 4 + nti];
        *(f32x4*)(fab + row * 64 + c * 4) = t;
      }
    }
    float run = 0.f;
    int jstart = 0;
    #pragma unroll 1
    for (int jb = 0; jb < 64; jb += 8) {
      #pragma unroll
      for (int u = 0; u < 8; ++u) {
        const int j = jb + u;
        run += fab[j * 64 + lane];
        if ((tails >> j) & 1) {  // wave-uniform flush at run tail
          const int d = __builtin_amdgcn_readlane(dval, j);
          if (d >= 0) {
            if ((intmask >> j) & 1) {
              msgs[(size_t)d * HID + half * 64 + lane] = f2bf(run);
            } else {
              const int slot = (jstart == 0) ? 0 : 1;  // only first/last runs can straddle
              const size_t sb = ((size_t)et * NWIN + win) * 2 + slot;
              side_part[sb * 128 + half * 64 + lane] = run;
              if (lane == 0 && half == 0) side_dst[sb] = d;
            }
          }
          run = 0.f;
          jstart = j + 1;
        }
      }
    }
  }
}

// ---------------- boundary fixup: owner window sums fp32 partials, writes bf16 m ------
__global__ void fixup_kernel(const int* __restrict__ S,
                             const int* __restrict__ side_dst,
                             const float* __restrict__ side_part,
                             u16* __restrict__ m0, u16* __restrict__ m1)
{
  const int b = blockIdx.x;           // et*NWIN + win
  const int et = b / NWIN, win = b - et * NWIN;
  const int t = threadIdx.x;          // 0..127
  u16* __restrict__ m = et ? m1 : m0;
  #pragma unroll
  for (int s = 0; s < 2; ++s) {
    const int d = side_dst[b * 2 + s];
    if (d < 0) continue;
    const int r0 = S[et * CELLS + d] - et * NE;
    if ((r0 >> 6) != win) continue;   // not the owner window (64-edge windows)
    const int w1 = (S[et * CELLS + d + 1] - et * NE - 1) >> 6;
    float sum = 0.f;
    for (int wi = win; wi <= w1; ++wi) {
      const int base = (et * NWIN + wi) * 2;
      if (side_dst[base + 0] == d) sum += side_part[(size_t)(base + 0) * 128 + t];
      if (side_dst[base + 1] == d) sum += side_part[(size_t)(base + 1) * 128 + t];
    }
    m[(size_t)d * HID + t] = f2bf(sum);
  }
}

// ---------------- fused LSTM: gates GEMM (K=512) + in-register activations + score -------
// R12 config (measured best): R10 block-cooperative DMA pipeline, M=128 cell-tiles,
// step-0 rh-chunk skip (kmax=6, bit-exact). Unchanged this round.
__launch_bounds__(512, 2)
__global__ void lstm_kernel(
    const int step,
    const u16* __restrict__ xb, const u16* __restrict__ mm0, const u16* __restrict__ mm1,
    u16* __restrict__ h, u16* __restrict__ rc,
    const u16* __restrict__ Wcb, const float* __restrict__ swp,
    float* __restrict__ out)
{
  __shared__ u16 wbuf[2][512 * 64];  // 128KB: W K-chunks [n=512][8 grp x 8], swizzled
  __shared__ u16 abuf[2][128 * 64];  // 32KB: A K-chunks [cell=128][8 grp x 8], swizzled
  const int tid = threadIdx.x;
  const int cb = blockIdx.x * 128;
  const int w = tid >> 6, lane = tid & 63, q = lane >> 4, c = lane & 15;

  const f32x4 zf = {0.f, 0.f, 0.f, 0.f};
  f32x4 acc[8][4];  // [cell-tile][gate] -- 128 AGPR
  #pragma unroll
  for (int mt = 0; mt < 8; ++mt)
    #pragma unroll
    for (int g = 0; g < 4; ++g) acc[mt][g] = zf;

  #define STAGE_A(kc, buf)                                                           \
    {                                                                                \
      _Pragma("unroll")                                                              \
      for (int i = 0; i < 2; ++i) {                                                  \
        const int idx = i * 512 + tid;                                               \
        const int cl = idx >> 3, lg = idx & 7;                                       \
        const int col = (((kc) & 1) << 6) + ((lg ^ (cl & 7)) << 3);                  \
        const int sel = (kc) >> 1;                                                   \
        const u16* srcp;                                                             \
        if (sel == 0)      srcp = xb  + (size_t)(cb + cl) * 128 + col;               \
        else if (sel == 1) srcp = mm0 + (size_t)(cb + cl) * 128 + col;               \
        else if (sel == 2) srcp = mm1 + (size_t)(cb + cl) * 128 + col;               \
        else               srcp = h   + (size_t)(cb + cl) * 128 + col;               \
        gload_lds16(srcp, abuf[buf] + i * 4096 + w * 512);                           \
      }                                                                              \
    }
  #define STAGE_W(kc, buf)                                                           \
    {                                                                                \
      _Pragma("unroll")                                                              \
      for (int i = 0; i < 8; ++i)                                                    \
        gload_lds16(Wcb + (size_t)(kc) * 32768 + i * 4096 + tid * 8,                 \
                    wbuf[buf] + i * 4096 + w * 512);                                 \
    }

  STAGE_A(0, 0);
  STAGE_W(0, 0);
  asm volatile("s_waitcnt vmcnt(0)" ::: "memory");
  __syncthreads();

  const int kmax = (step == 0) ? 6 : 8;  // step 0: rh == 0 -> skip chunks 6,7 (exact)
  #pragma unroll 1
  for (int kc = 0; kc < kmax; ++kc) {
    if (kc + 1 < kmax) {
      STAGE_A(kc + 1, (kc + 1) & 1);
      STAGE_W(kc + 1, (kc + 1) & 1);
    }
    const u16* ac = abuf[kc & 1];
    const u16* wc = wbuf[kc & 1];
    #pragma unroll
    for (int kk = 0; kk < 2; ++kk) {
      const int lg = kk * 4 + q;
      short8 a[8], b[4];
      #pragma unroll
      for (int mt = 0; mt < 8; ++mt) {
        const int row = mt * 16 + c;
        a[mt] = *(const short8*)(ac + row * 64 + ((lg ^ (row & 7)) << 3));
      }
      #pragma unroll
      for (int g = 0; g < 4; ++g) {
        const int n = g * 128 + w * 16 + c;
        b[g] = *(const short8*)(wc + n * 64 + ((lg ^ (n & 7)) << 3));
      }
      #pragma unroll
      for (int mt = 0; mt < 8; ++mt)
        #pragma unroll
        for (int g = 0; g < 4; ++g)
          acc[mt][g] = __builtin_amdgcn_mfma_f32_16x16x32_bf16(a[mt], b[g], acc[mt][g], 0, 0, 0);
    }
    // next chunk's DMAs were covered by this chunk's MFMA; pay only the residual
    asm volatile("s_waitcnt vmcnt(0)" ::: "memory");
    __syncthreads();
  }
  #undef STAGE_A
  #undef STAGE_W

  // in-register LSTM epilogue: lane (q,c) per (mt,r): cell = mt*16+4q+r, feat = w*16+c
  const float swc = swp[w * 16 + c];
  const bool last = (step == NSTEPS - 1);
  float* pt = (float*)abuf;  // [8 waves][128 cells] score partials (reuse A buffers)
  #pragma unroll
  for (int mt = 0; mt < 8; ++mt) {
    #pragma unroll
    for (int r = 0; r < 4; ++r) {
      const int cl = mt * 16 + 4 * q + r;
      const int cell = cb + cl;
      const float ig = sigm(acc[mt][0][r]);
      const float fg = sigm(acc[mt][1][r]);
      const float gg = tanha(acc[mt][2][r]);
      const float og = sigm(acc[mt][3][r]);
      u16* rcp = rc + (size_t)cell * HID + w * 16 + c;
      const float c0 = (step == 0) ? 0.f : bf2f(rcp[0]);
      const float nc = fg * c0 + ig * gg;
      const float nhv = og * tanha(nc);
      if (!last) {
        rcp[0] = f2bf(nc);
        h[(size_t)cell * HID + w * 16 + c] = f2bf(nhv);
      }
      float v = nhv * swc;  // score partial, reduce over c (16 feats)
      v += __shfl_xor(v, 1); v += __shfl_xor(v, 2);
      v += __shfl_xor(v, 4); v += __shfl_xor(v, 8);
      if (c == 0) pt[w * 128 + cl] = v;
    }
  }
  __syncthreads();
  if (tid < 128) {
    float s = 0.f;
    #pragma unroll
    for (int ww = 0; ww < 8; ++ww) s += pt[ww * 128 + tid];
    out[step * CELLS + cb + tid] = s;
  }
}

extern "C" void kernel_launch(void* const* d_in, const int* in_sizes, int n_in,
                              void* d_out, int out_size, void* d_ws, size_t ws_size,
                              hipStream_t stream)
{
  const int* q      = (const int*)d_in[0];
  const int* esrc   = (const int*)d_in[1];
  const int* edst   = (const int*)d_in[2];
  const float* embed= (const float*)d_in[3];
  const float* W0   = (const float*)d_in[4];
  const float* b0   = (const float*)d_in[5];
  const float* W1   = (const float*)d_in[6];
  const float* b1   = (const float*)d_in[7];
  const float* W2   = (const float*)d_in[8];
  const float* b2   = (const float*)d_in[9];
  const float* W3   = (const float*)d_in[10];
  const float* b3   = (const float*)d_in[11];
  const float* Wih  = (const float*)d_in[12];
  const float* Whh  = (const float*)d_in[13];
  const float* sw   = (const float*)d_in[14];

  char* ws = (char*)d_ws;
  size_t off = 0;
  auto alloc = [&](size_t bytes) {
    void* p = ws + off;
    off += (bytes + 255) & ~(size_t)255;
    return p;
  };
  u16*   h    = (u16*)  alloc((size_t)CELLS * HID * 2);
  u16*   xb   = (u16*)  alloc((size_t)CELLS * HID * 2);
  u16*   rc   = (u16*)  alloc((size_t)CELLS * HID * 2);  // bf16 carry
  u16*   m0   = (u16*)  alloc((size_t)CELLS * HID * 2);  // bf16; m1 contiguous after
  u16*   m1   = (u16*)  alloc((size_t)CELLS * HID * 2);
  u16*   W0b  = (u16*)  alloc(2 * 128 * 256 * 2);
  u16*   W123b= (u16*)  alloc((size_t)3 * 2 * 128 * 128 * 2);  // layers 1..3 contiguous
  u16*   Wcb  = (u16*)  alloc(512 * 512 * 2);  // Wcb2 chunk-swizzled layout
  float* bp   = (float*)alloc(4 * 256 * 4);
  float* swp  = (float*)alloc(128 * 4);
  // sort workspace -- counts & fill ADJACENT (one memset covers both)
  int*   counts = (int*)alloc((size_t)2 * CELLS * 4);
  int*   fill   = (int*)alloc((size_t)2 * CELLS * 4);
  int*   Sarr   = (int*)alloc(((size_t)2 * CELLS + 1) * 4);
  int*   btot   = (int*)alloc(192 * 4);
  int2*  sp     = (int2*)alloc((size_t)2 * NE * 8);  // packed (src,dst) sorted pairs
  // boundary side buffers
  int*   side_dst  = (int*)  alloc((size_t)2 * NWIN * 2 * 4);
  float* side_part = (float*)alloc((size_t)2 * NWIN * 2 * 128 * 4);

  // prep grid: 65536+98304+262144+1024+128 = 427136 -> 1669 blocks of 256
  prep_kernel<<<1669, 256, 0, stream>>>(W0, W1, W2, W3, b0, b1, b2, b3, Wih, Whh, sw,
                                        W0b, W123b, Wcb, bp, swp);
  init_kernel<<<(CELLS * HID) / 256, 256, 0, stream>>>(q, embed, xb, h);

  // dst-sort both edge types (counts+fill zeroed in ONE memset)
  hipMemsetAsync(counts, 0, (size_t)4 * CELLS * 4, stream);
  hist_kernel<<<(2 * NE + 255) / 256, 256, 0, stream>>>(edst, counts);
  scan1_kernel<<<192, 1024, 0, stream>>>(counts, Sarr, btot);
  scan23_kernel<<<192, 1024, 0, stream>>>(btot, Sarr);
  scatter_kernel<<<(2 * NE + 255) / 256, 256, 0, stream>>>(esrc, edst, Sarr, fill, sp);

  // m zeroing hoisted out of the step loop: every dst with >=1 edge gets its full row
  // rewritten each step (interior flush or fixup); zero-degree rows stay zero. side_dst
  // values are step-invariant (same sorted graph), so one 0xFF fill suffices.
  hipMemsetAsync(m0, 0, (size_t)2 * CELLS * HID * 2, stream);        // m0+m1 (bf16)
  hipMemsetAsync(side_dst, 0xFF, (size_t)2 * NWIN * 2 * 4, stream);  // dst = -1

  for (int step = 0; step < NSTEPS; ++step) {
    msg_kernel<<<dim3((NE + 511) / 512, 2), 512, 0, stream>>>(h, sp, Sarr,
                                                              W0b, W123b, bp,
                                                              m0, m1, side_dst, side_part);
    fixup_kernel<<<2 * NWIN, 128, 0, stream>>>(Sarr, side_dst, side_part, m0, m1);
    lstm_kernel<<<CELLS / 128, 512, 0, stream>>>(step, xb, m0, m1, h, rc, Wcb, swp,
                                                 (float*)d_out);
  }
}

// Round 15
// 652.774 us; speedup vs baseline: 1.0115x; 1.0115x over previous
//
#include <hip/hip_runtime.h>

#define HID 128
#define CELLS 98304
#define NE 250000
#define NSTEPS 2
#define NWIN 3912  // 64-edge windows per edge type = 489 blocks * 8 waves

typedef __attribute__((ext_vector_type(8))) short short8;
typedef __attribute__((ext_vector_type(4))) float f32x4;
typedef __attribute__((ext_vector_type(4))) unsigned int u32x4;
typedef unsigned short u16;

// pi permutation: pi-slot s <-> natural col permf(s)
__device__ __forceinline__ int permf(int s) { return ((s & 7) << 4) | (s >> 3); }
// m storage position p: half = p>>6, lane = p&63,
// pi-slot = (lane>>2)*8 + half*4 + (lane&3); natural col = permf(slot)
__device__ __forceinline__ int nat_of_pos(int p) {
  int l = p & 63, hf = p >> 6;
  int slot = ((l >> 2) << 3) + (hf << 2) + (l & 3);
  return ((slot & 7) << 4) | (slot >> 3);
}

__device__ __forceinline__ u16 f2bf(float f) {
  unsigned int u = __builtin_bit_cast(unsigned int, f);
  u += 0x7fffu + ((u >> 16) & 1u);
  return (u16)(u >> 16);
}
__device__ __forceinline__ float bf2f(u16 s) {
  unsigned int u = ((unsigned int)s) << 16;
  return __builtin_bit_cast(float, u);
}
// packed f32x2 -> bf16x2 (RNE), lo -> D[15:0], hi -> D[31:16]
__device__ __forceinline__ unsigned int cvtpk_bf16(float lo, float hi) {
  unsigned int r;
  asm("v_cvt_pk_bf16_f32 %0, %1, %2" : "=v"(r) : "v"(lo), "v"(hi));
  return r;
}
__device__ __forceinline__ float sigm(float x) { return 1.f / (1.f + __expf(-x)); }
__device__ __forceinline__ float tanha(float x) { return 1.f - 2.f / (__expf(2.f * x) + 1.f); }

// zero-register DMA: 16B per lane, global(per-lane addr) -> LDS (wave-uniform base + lane*16)
__device__ __forceinline__ void gload_lds16(const u16* g, u16* l) {
  __builtin_amdgcn_global_load_lds(
      (const __attribute__((address_space(1))) unsigned int*)(const void*)g,
      (__attribute__((address_space(3))) unsigned int*)(void*)l, 16, 0, 0);
}

// cooperative 16KB weight-chunk stage (msg): 512 threads x 2 insts x 16B, linear
__device__ __forceinline__ void stage_w(const u16* __restrict__ ws, u16* wl, int w, int lane) {
  #pragma unroll
  for (int i = 0; i < 2; ++i)
    gload_lds16(ws + i * 4096 + w * 512 + lane * 8, wl + i * 4096 + w * 512);
}

// ---------------- prep: bf16-convert weights ----------------
// W0b: [et][chunk t=0..3][n=128][s=64] -- K-chunks of 64, XOR-swizzled within chunk:
//   position group g' (0..7) of row n holds natural k-group g'^(n&7) of chunk t.
//   t=0,1: src half (k 0..127), t=2,3: dst half (k 128..255). Natural K (h order).
// W123b: [l-1][et][half hh][n][s=64], same per-chunk swizzle, K pi-permuted (tile order).
// Wcb2: [kc=0..7][n=0..511][g'=0..7][j=0..7] -- lstm gates weights in K-chunks of
//   64, XOR-swizzled within chunk; K = [Wih(x | m0 | m1) | Whh], m-blocks m-storage order.
__global__ void prep_kernel(
    const float* __restrict__ W0, const float* __restrict__ W1,
    const float* __restrict__ W2, const float* __restrict__ W3,
    const float* __restrict__ b0, const float* __restrict__ b1,
    const float* __restrict__ b2, const float* __restrict__ b3,
    const float* __restrict__ Wih, const float* __restrict__ Whh,
    const float* __restrict__ sw,
    u16* __restrict__ W0b, u16* __restrict__ W123b,
    u16* __restrict__ Wcb, float* __restrict__ bp, float* __restrict__ swp)
{
  int idx = blockIdx.x * 256 + threadIdx.x;
  if (idx < 65536) {  // W0b swizzled chunks
    int et = idx >> 15, t = (idx >> 13) & 3, n = (idx >> 6) & 127, s = idx & 63;
    int g = s >> 3, j = s & 7;
    int gn = g ^ (n & 7);
    W0b[idx] = f2bf(W0[(et * 128 + n) * 256 + t * 64 + gn * 8 + j]);
    return;
  }
  idx -= 65536;
  if (idx < 98304) {  // W123b swizzled half-chunks, K pi-permuted
    int which = idx >> 15, r = idx & 32767;
    int et = r >> 14, hh = (r >> 13) & 1, n = (r >> 6) & 127, s = r & 63;
    int g = s >> 3, j = s & 7;
    int gn = g ^ (n & 7);
    const float* W = which == 0 ? W1 : (which == 1 ? W2 : W3);
    W123b[which * 32768 + r] = f2bf(W[(et * 128 + n) * 128 + permf(hh * 64 + gn * 8 + j)]);
    return;
  }
  idx -= 98304;
  if (idx < 262144) {  // Wcb2 chunk-swizzled lstm weights
    int kc = idx >> 15, r = idx & 32767;
    int n = r >> 6, s = r & 63;
    int gp = s >> 3, j = s & 7;
    int k = kc * 64 + ((gp ^ (n & 7)) << 3) + j;   // natural concat-K position
    int blk = k >> 7, s7 = k & 127;
    int k7 = (blk == 1 || blk == 2) ? nat_of_pos(s7) : s7;  // x / rh natural
    float v = (blk < 3) ? Wih[n * 384 + blk * 128 + k7] : Whh[n * 128 + k7];
    Wcb[idx] = f2bf(v);
    return;
  }
  idx -= 262144;
  if (idx < 1024) {  // biases [layer 0..3][et][slot] pi-order
    int l = idx >> 8, r = idx & 255;
    int et = r >> 7, s = r & 127;
    const float* b = l == 0 ? b0 : (l == 1 ? b1 : (l == 2 ? b2 : b3));
    bp[idx] = b[et * 128 + permf(s)];
    return;
  }
  idx -= 1024;
  if (idx < 128) swp[idx] = sw[idx];
}

// ---------------- init: x = embed[q] (natural, bf16), h = x (rc untouched:
// step 0 never reads it). Reads the 1.5KB f32 embed table directly (L1-resident).
__global__ void init_kernel(const int* __restrict__ q, const float* __restrict__ embed,
                            u16* __restrict__ xb, u16* __restrict__ h)
{
  int idx = blockIdx.x * 256 + threadIdx.x;
  int c = idx >> 7, s = idx & 127;
  u16 v = f2bf(embed[q[c] * 128 + s]);
  xb[idx] = v;
  h[idx] = v;
}

// ---------------- dst-sort pipeline: hist -> scan (2 kernels) -> scatter ----------------
__global__ void hist_kernel(const int* __restrict__ edst, int* __restrict__ counts)
{
  int idx = blockIdx.x * 256 + threadIdx.x;
  if (idx >= 2 * NE) return;
  int et = (idx >= NE) ? 1 : 0;
  atomicAdd(&counts[et * CELLS + edst[idx]], 1);
}

// R13: wave-level shfl scan (1 barrier) instead of 20-barrier Hillis-Steele.
__global__ void scan1_kernel(const int* __restrict__ counts, int* __restrict__ S,
                             int* __restrict__ btot)
{
  __shared__ int wsum[16];
  const int t = threadIdx.x, b = blockIdx.x;
  const int lane = t & 63, wv = t >> 6;
  const int i = b * 1024 + t;
  const int v = counts[i];
  // inclusive wave scan
  int acc = v;
  #pragma unroll
  for (int off = 1; off < 64; off <<= 1) {
    int n = __shfl_up(acc, off);
    if (lane >= off) acc += n;
  }
  if (lane == 63) wsum[wv] = acc;
  __syncthreads();
  int wpref = 0;
  for (int j = 0; j < wv; ++j) wpref += wsum[j];  // <=15 LDS broadcasts
  acc += wpref;
  S[i] = acc - v;  // block-local exclusive
  if (t == 1023) btot[b] = acc;
}

// R13: fused scan2+scan3 -- each block tree-reduces its own prefix of btot.
__global__ void scan23_kernel(const int* __restrict__ btot, int* __restrict__ S)
{
  __shared__ int sh[256];
  const int t = threadIdx.x, b = blockIdx.x;
  if (t < 256) sh[t] = (t < b) ? btot[t] : 0;  // b <= 191 < 256
  __syncthreads();
  #pragma unroll
  for (int off = 128; off > 0; off >>= 1) {
    if (t < off) sh[t] += sh[t + off];
    __syncthreads();
  }
  const int boff = sh[0];
  S[b * 1024 + t] += boff;
  if (b == 0 && t == 0) S[2 * CELLS] = 2 * NE;
}

// R15: reverted R14's int2 packing (neutral-to-negative; pre-loop is atomic-latency
// bound, not store-transaction bound). Back to the R13 measured-best form.
__global__ void scatter_kernel(const int* __restrict__ esrc, const int* __restrict__ edst,
                               const int* __restrict__ S, int* __restrict__ fill,
                               int* __restrict__ ssrc, int* __restrict__ sdst)
{
  int idx = blockIdx.x * 256 + threadIdx.x;
  if (idx >= 2 * NE) return;
  int et = (idx >= NE) ? 1 : 0;
  int d = edst[idx];
  int pos = atomicAdd(&fill[et * CELLS + d], 1);
  int slot = S[et * CELLS + d] - et * NE + pos;  // et-local sorted slot
  sdst[et * NE + slot] = d;
  ssrc[et * NE + slot] = esrc[idx];
}

// bias + relu + pack-transpose into swizzled per-wave LDS A-tile (pitch 128, 8-col XOR
// swizzle). Packed conversion via cvt_pk (R6).
__device__ __forceinline__ void bias_relu_store(f32x4 (&acc)[4][8], const float* __restrict__ bl,
                                                u16* __restrict__ ab, int q, int c)
{
  float bias[8];
  #pragma unroll
  for (int j = 0; j < 8; ++j) bias[j] = bl[c * 8 + j];
  #pragma unroll
  for (int mt = 0; mt < 4; ++mt) {
    #pragma unroll
    for (int r = 0; r < 4; ++r) {
      const int rowl = mt * 16 + 4 * q + r;
      u32x4 t;
      #pragma unroll
      for (int p = 0; p < 4; ++p) {
        float v0 = acc[mt][2 * p][r] + bias[2 * p];
        float v1 = acc[mt][2 * p + 1][r] + bias[2 * p + 1];
        v0 = v0 > 0.f ? v0 : 0.f;
        v1 = v1 > 0.f ? v1 : 0.f;
        t[p] = cvtpk_bf16(v0, v1);
      }
      *(u32x4*)(ab + rowl * 128 + ((c ^ (rowl & 15)) << 3)) = t;
    }
  }
}

// ---------------- fused 4-layer edge MLP + sorted segmented-sum scatter ----------------
// Measured-best R6 config: 8-wave blocks, 64-edge wave-private windows, 10-chunk
// 2-deep block-cooperative wbuf pipeline (global_load_lds DMA), h[src] rows DMA-staged
// into XOR-swizzled per-wave A-tiles, cvt_pk bf16 packing, zero bank conflicts.
// Session ladder: 232 -> 177 (R4 LDS weight chunks) -> 165 (R5 2-deep pipeline)
// -> 160 (R6 cvt_pk) -> ~152 us. Residual = per-phase convoy at 1 block/CU;
// occupancy (R2/R8), code-size (R1), src-DMA (R3), L0 factorization (R7) all probed.
__launch_bounds__(512, 2)
__global__ void msg_kernel(
    const u16* __restrict__ h,
    const int* __restrict__ ssrc, const int* __restrict__ sdst,
    const int* __restrict__ S,
    const u16* __restrict__ W0b, const u16* __restrict__ W123b,
    const float* __restrict__ bp,
    u16* __restrict__ m0, u16* __restrict__ m1,
    int* __restrict__ side_dst, float* __restrict__ side_part)
{
  __shared__ u16 abuf[8][64 * 128];   // 128KB: wave-private A-tiles, XOR-swizzled
  __shared__ u16 wbuf[2][128 * 64];   // 32KB: double-buffered weight chunk [n=128][k=64]
  const int et = blockIdx.y;
  const int tid = threadIdx.x;
  const int w = tid >> 6, lane = tid & 63, q = lane >> 4, c = lane & 15;
  const int ebase = blockIdx.x * 512 + w * 64;  // et-local sorted slot base for this wave
  const int win = blockIdx.x * 8 + w;
  const int* __restrict__ src = ssrc + et * NE;
  const int* __restrict__ dst = sdst + et * NE;
  u16* __restrict__ msgs = (et == 0) ? m0 : m1;
  u16* ab = abuf[w];

  // per-lane src row for DMA staging; per-lane dst rows for register gathers
  int eS = ebase + lane;
  if (eS >= NE) eS = NE - 1;
  const int srow = src[eS];

  int rowD[4];
  #pragma unroll
  for (int mt = 0; mt < 4; ++mt) {
    int e = ebase + mt * 16 + c;
    if (e >= NE) e = NE - 1;
    rowD[mt] = dst[e];
  }

  // issue 16 zero-register DMA gathers: h[src] rows -> own swizzled LDS tile.
  // position (row r, group cg) holds natural group cg ^ (r&15).
  #pragma unroll
  for (int i = 0; i < 16; ++i) {
    const int r = i * 4 + (lane >> 4);
    const int grow = __shfl(srow, r);
    const int cg = lane & 15;
    gload_lds16(h + (size_t)grow * 128 + ((cg ^ (r & 15)) << 3), ab + i * 512);
  }
  // chunk 0 (W0 t=2) into wbuf[0]; nobody reads wbuf before the prologue barrier
  stage_w(W0b + (et * 4 + 2) * 8192, wbuf[0], w, lane);

  // run structure (wave-uniform masks). Cross-lane ops unconditional.
  const int eL = ebase + lane;
  const int dval = (eL < NE) ? dst[eL] : -1;
  int rpS = 0, rpE = 0;
  if (dval >= 0) {
    rpS = S[et * CELLS + dval] - et * NE;
    rpE = S[et * CELLS + dval + 1] - et * NE;
  }
  const int dlagged = __shfl_up(dval, 1);          // all 64 lanes active
  const bool headp = (lane == 0) | (dval != dlagged);
  const unsigned long long tails = (__ballot(headp) >> 1) | (1ull << 63);
  const unsigned long long intmask = __ballot(dval >= 0 && rpS >= ebase && rpE <= ebase + 64);

  const f32x4 zf = {0.f, 0.f, 0.f, 0.f};
  f32x4 acc[4][8];
  #pragma unroll
  for (int mt = 0; mt < 4; ++mt)
    #pragma unroll
    for (int nt = 0; nt < 8; ++nt) acc[mt][nt] = zf;

  asm volatile("s_waitcnt vmcnt(0)" ::: "memory");  // A-DMAs + chunk 0 landed
  __syncthreads();

  // ---- 10-chunk pipelined K-loop ----
  #pragma unroll 1
  for (int i = 0; i < 10; ++i) {
    // stage next chunk into the buffer whose readers finished at the previous barrier
    if (i < 9) {
      const int j = i + 1;
      const u16* wsrc;
      if (j < 4) {
        const int t = (j < 2) ? (j + 2) : (j - 2);
        wsrc = W0b + (et * 4 + t) * 8192;
      } else {
        const int li = j - 4;  // (l-1)*2 + hh
        wsrc = W123b + (li >> 1) * 32768 + et * 16384 + (li & 1) * 8192;
      }
      stage_w(wsrc, wbuf[j & 1], w, lane);
    }
    // at the start of each layer chunk-pair: flush previous layer into own A-tile
    if (i >= 4 && !(i & 1)) {
      bias_relu_store(acc, bp + ((i - 4) >> 1) * 256 + et * 128, ab, q, c);
      #pragma unroll
      for (int mt = 0; mt < 4; ++mt)
        #pragma unroll
        for (int nt = 0; nt < 8; ++nt) acc[mt][nt] = zf;
    }
    const u16* wb = wbuf[i & 1];
    #pragma unroll
    for (int ks = 0; ks < 2; ++ks) {
      short8 a[4], b[8];
      if (i < 2) {  // dst half of L0: register gathers (sorted runs -> cache hits)
        const int kqh = i * 64 + ks * 32 + q * 8;
        #pragma unroll
        for (int mt = 0; mt < 4; ++mt)
          a[mt] = *(const short8*)(h + (size_t)rowD[mt] * HID + kqh);
      } else {      // src half of L0 / layers 1-3: own swizzled A-tile
        const int blk = (i & 1) * 8 + ks * 4 + q;
        #pragma unroll
        for (int mt = 0; mt < 4; ++mt) {
          const int row = mt * 16 + c;
          a[mt] = *(const short8*)(ab + row * 128 + ((blk ^ c) << 3));
        }
      }
      #pragma unroll
      for (int nt = 0; nt < 8; ++nt)
        b[nt] = *(const short8*)(wb + (nt * 16 + c) * 64 + (((ks * 4 + q) ^ (c & 7)) << 3));
      #pragma unroll
      for (int mt = 0; mt < 4; ++mt)
        #pragma unroll
        for (int nt = 0; nt < 8; ++nt)
          acc[mt][nt] = __builtin_amdgcn_mfma_f32_16x16x32_bf16(a[mt], b[nt], acc[mt][nt], 0, 0, 0);
    }
    // next chunk's DMA latency was covered by this compute; pay only the residual
    asm volatile("s_waitcnt vmcnt(0)" ::: "memory");
    __syncthreads();
  }

  // layer-3 epilogue: +bias into fp32 fab (two 64-feature passes), column scan; interior
  // flush = 128B coalesced bf16 store; boundary flush = fp32 partial to side buffer.
  float bias[8];
  #pragma unroll
  for (int j = 0; j < 8; ++j) bias[j] = bp[3 * 256 + et * 128 + c * 8 + j];

  float* fab = (float*)ab;  // 64 rows x 64 feature-slots fp32 (16KB, wave-private)
  #pragma unroll
  for (int half = 0; half < 2; ++half) {
    #pragma unroll
    for (int mt = 0; mt < 4; ++mt) {
      #pragma unroll
      for (int r = 0; r < 4; ++r) {
        const int row = mt * 16 + 4 * q + r;
        f32x4 t;
        #pragma unroll
        for (int nti = 0; nti < 4; ++nti)
          t[nti] = acc[mt][half * 4 + nti][r] + bias[half * 4 + nti];
        *(f32x4*)(fab + row * 64 + c * 4) = t;
      }
    }
    float run = 0.f;
    int jstart = 0;
    #pragma unroll 1
    for (int jb = 0; jb < 64; jb += 8) {
      #pragma unroll
      for (int u = 0; u < 8; ++u) {
        const int j = jb + u;
        run += fab[j * 64 + lane];
        if ((tails >> j) & 1) {  // wave-uniform flush at run tail
          const int d = __builtin_amdgcn_readlane(dval, j);
          if (d >= 0) {
            if ((intmask >> j) & 1) {
              msgs[(size_t)d * HID + half * 64 + lane] = f2bf(run);
            } else {
              const int slot = (jstart == 0) ? 0 : 1;  // only first/last runs can straddle
              const size_t sb = ((size_t)et * NWIN + win) * 2 + slot;
              side_part[sb * 128 + half * 64 + lane] = run;
              if (lane == 0 && half == 0) side_dst[sb] = d;
            }
          }
          run = 0.f;
          jstart = j + 1;
        }
      }
    }
  }
}

// ---------------- boundary fixup: owner window sums fp32 partials, writes bf16 m ------
__global__ void fixup_kernel(const int* __restrict__ S,
                             const int* __restrict__ side_dst,
                             const float* __restrict__ side_part,
                             u16* __restrict__ m0, u16* __restrict__ m1)
{
  const int b = blockIdx.x;           // et*NWIN + win
  const int et = b / NWIN, win = b - et * NWIN;
  const int t = threadIdx.x;          // 0..127
  u16* __restrict__ m = et ? m1 : m0;
  #pragma unroll
  for (int s = 0; s < 2; ++s) {
    const int d = side_dst[b * 2 + s];
    if (d < 0) continue;
    const int r0 = S[et * CELLS + d] - et * NE;
    if ((r0 >> 6) != win) continue;   // not the owner window (64-edge windows)
    const int w1 = (S[et * CELLS + d + 1] - et * NE - 1) >> 6;
    float sum = 0.f;
    for (int wi = win; wi <= w1; ++wi) {
      const int base = (et * NWIN + wi) * 2;
      if (side_dst[base + 0] == d) sum += side_part[(size_t)(base + 0) * 128 + t];
      if (side_dst[base + 1] == d) sum += side_part[(size_t)(base + 1) * 128 + t];
    }
    m[(size_t)d * HID + t] = f2bf(sum);
  }
}

// ---------------- fused LSTM: gates GEMM (K=512) + in-register activations + score -------
// Measured-best R12 config: block-cooperative 2-deep DMA pipeline, M=128 cell-tiles
// (halved W-traffic vs M=64), step-0 rh-chunk skip (kmax=6, bit-exact).
__launch_bounds__(512, 2)
__global__ void lstm_kernel(
    const int step,
    const u16* __restrict__ xb, const u16* __restrict__ mm0, const u16* __restrict__ mm1,
    u16* __restrict__ h, u16* __restrict__ rc,
    const u16* __restrict__ Wcb, const float* __restrict__ swp,
    float* __restrict__ out)
{
  __shared__ u16 wbuf[2][512 * 64];  // 128KB: W K-chunks [n=512][8 grp x 8], swizzled
  __shared__ u16 abuf[2][128 * 64];  // 32KB: A K-chunks [cell=128][8 grp x 8], swizzled
  const int tid = threadIdx.x;
  const int cb = blockIdx.x * 128;
  const int w = tid >> 6, lane = tid & 63, q = lane >> 4, c = lane & 15;

  const f32x4 zf = {0.f, 0.f, 0.f, 0.f};
  f32x4 acc[8][4];  // [cell-tile][gate] -- 128 AGPR
  #pragma unroll
  for (int mt = 0; mt < 8; ++mt)
    #pragma unroll
    for (int g = 0; g < 4; ++g) acc[mt][g] = zf;

  #define STAGE_A(kc, buf)                                                           \
    {                                                                                \
      _Pragma("unroll")                                                              \
      for (int i = 0; i < 2; ++i) {                                                  \
        const int idx = i * 512 + tid;                                               \
        const int cl = idx >> 3, lg = idx & 7;                                       \
        const int col = (((kc) & 1) << 6) + ((lg ^ (cl & 7)) << 3);                  \
        const int sel = (kc) >> 1;                                                   \
        const u16* srcp;                                                             \
        if (sel == 0)      srcp = xb  + (size_t)(cb + cl) * 128 + col;               \
        else if (sel == 1) srcp = mm0 + (size_t)(cb + cl) * 128 + col;               \
        else if (sel == 2) srcp = mm1 + (size_t)(cb + cl) * 128 + col;               \
        else               srcp = h   + (size_t)(cb + cl) * 128 + col;               \
        gload_lds16(srcp, abuf[buf] + i * 4096 + w * 512);                           \
      }                                                                              \
    }
  #define STAGE_W(kc, buf)                                                           \
    {                                                                                \
      _Pragma("unroll")                                                              \
      for (int i = 0; i < 8; ++i)                                                    \
        gload_lds16(Wcb + (size_t)(kc) * 32768 + i * 4096 + tid * 8,                 \
                    wbuf[buf] + i * 4096 + w * 512);                                 \
    }

  STAGE_A(0, 0);
  STAGE_W(0, 0);
  asm volatile("s_waitcnt vmcnt(0)" ::: "memory");
  __syncthreads();

  const int kmax = (step == 0) ? 6 : 8;  // step 0: rh == 0 -> skip chunks 6,7 (exact)
  #pragma unroll 1
  for (int kc = 0; kc < kmax; ++kc) {
    if (kc + 1 < kmax) {
      STAGE_A(kc + 1, (kc + 1) & 1);
      STAGE_W(kc + 1, (kc + 1) & 1);
    }
    const u16* ac = abuf[kc & 1];
    const u16* wc = wbuf[kc & 1];
    #pragma unroll
    for (int kk = 0; kk < 2; ++kk) {
      const int lg = kk * 4 + q;
      short8 a[8], b[4];
      #pragma unroll
      for (int mt = 0; mt < 8; ++mt) {
        const int row = mt * 16 + c;
        a[mt] = *(const short8*)(ac + row * 64 + ((lg ^ (row & 7)) << 3));
      }
      #pragma unroll
      for (int g = 0; g < 4; ++g) {
        const int n = g * 128 + w * 16 + c;
        b[g] = *(const short8*)(wc + n * 64 + ((lg ^ (n & 7)) << 3));
      }
      #pragma unroll
      for (int mt = 0; mt < 8; ++mt)
        #pragma unroll
        for (int g = 0; g < 4; ++g)
          acc[mt][g] = __builtin_amdgcn_mfma_f32_16x16x32_bf16(a[mt], b[g], acc[mt][g], 0, 0, 0);
    }
    // next chunk's DMAs were covered by this chunk's MFMA; pay only the residual
    asm volatile("s_waitcnt vmcnt(0)" ::: "memory");
    __syncthreads();
  }
  #undef STAGE_A
  #undef STAGE_W

  // in-register LSTM epilogue: lane (q,c) per (mt,r): cell = mt*16+4q+r, feat = w*16+c
  const float swc = swp[w * 16 + c];
  const bool last = (step == NSTEPS - 1);
  float* pt = (float*)abuf;  // [8 waves][128 cells] score partials (reuse A buffers)
  #pragma unroll
  for (int mt = 0; mt < 8; ++mt) {
    #pragma unroll
    for (int r = 0; r < 4; ++r) {
      const int cl = mt * 16 + 4 * q + r;
      const int cell = cb + cl;
      const float ig = sigm(acc[mt][0][r]);
      const float fg = sigm(acc[mt][1][r]);
      const float gg = tanha(acc[mt][2][r]);
      const float og = sigm(acc[mt][3][r]);
      u16* rcp = rc + (size_t)cell * HID + w * 16 + c;
      const float c0 = (step == 0) ? 0.f : bf2f(rcp[0]);
      const float nc = fg * c0 + ig * gg;
      const float nhv = og * tanha(nc);
      if (!last) {
        rcp[0] = f2bf(nc);
        h[(size_t)cell * HID + w * 16 + c] = f2bf(nhv);
      }
      float v = nhv * swc;  // score partial, reduce over c (16 feats)
      v += __shfl_xor(v, 1); v += __shfl_xor(v, 2);
      v += __shfl_xor(v, 4); v += __shfl_xor(v, 8);
      if (c == 0) pt[w * 128 + cl] = v;
    }
  }
  __syncthreads();
  if (tid < 128) {
    float s = 0.f;
    #pragma unroll
    for (int ww = 0; ww < 8; ++ww) s += pt[ww * 128 + tid];
    out[step * CELLS + cb + tid] = s;
  }
}

extern "C" void kernel_launch(void* const* d_in, const int* in_sizes, int n_in,
                              void* d_out, int out_size, void* d_ws, size_t ws_size,
                              hipStream_t stream)
{
  const int* q      = (const int*)d_in[0];
  const int* esrc   = (const int*)d_in[1];
  const int* edst   = (const int*)d_in[2];
  const float* embed= (const float*)d_in[3];
  const float* W0   = (const float*)d_in[4];
  const float* b0   = (const float*)d_in[5];
  const float* W1   = (const float*)d_in[6];
  const float* b1   = (const float*)d_in[7];
  const float* W2   = (const float*)d_in[8];
  const float* b2   = (const float*)d_in[9];
  const float* W3   = (const float*)d_in[10];
  const float* b3   = (const float*)d_in[11];
  const float* Wih  = (const float*)d_in[12];
  const float* Whh  = (const float*)d_in[13];
  const float* sw   = (const float*)d_in[14];

  char* ws = (char*)d_ws;
  size_t off = 0;
  auto alloc = [&](size_t bytes) {
    void* p = ws + off;
    off += (bytes + 255) & ~(size_t)255;
    return p;
  };
  u16*   h    = (u16*)  alloc((size_t)CELLS * HID * 2);
  u16*   xb   = (u16*)  alloc((size_t)CELLS * HID * 2);
  u16*   rc   = (u16*)  alloc((size_t)CELLS * HID * 2);  // bf16 carry
  u16*   m0   = (u16*)  alloc((size_t)CELLS * HID * 2);  // bf16; m1 contiguous after
  u16*   m1   = (u16*)  alloc((size_t)CELLS * HID * 2);
  u16*   W0b  = (u16*)  alloc(2 * 128 * 256 * 2);
  u16*   W123b= (u16*)  alloc((size_t)3 * 2 * 128 * 128 * 2);  // layers 1..3 contiguous
  u16*   Wcb  = (u16*)  alloc(512 * 512 * 2);  // Wcb2 chunk-swizzled layout
  float* bp   = (float*)alloc(4 * 256 * 4);
  float* swp  = (float*)alloc(128 * 4);
  // sort workspace -- counts & fill ADJACENT (one memset covers both)
  int*   counts = (int*)alloc((size_t)2 * CELLS * 4);
  int*   fill   = (int*)alloc((size_t)2 * CELLS * 4);
  int*   Sarr   = (int*)alloc(((size_t)2 * CELLS + 1) * 4);
  int*   btot   = (int*)alloc(192 * 4);
  int*   ssrc   = (int*)alloc((size_t)2 * NE * 4);
  int*   sdst   = (int*)alloc((size_t)2 * NE * 4);
  // boundary side buffers
  int*   side_dst  = (int*)  alloc((size_t)2 * NWIN * 2 * 4);
  float* side_part = (float*)alloc((size_t)2 * NWIN * 2 * 128 * 4);

  // prep grid: 65536+98304+262144+1024+128 = 427136 -> 1669 blocks of 256
  prep_kernel<<<1669, 256, 0, stream>>>(W0, W1, W2, W3, b0, b1, b2, b3, Wih, Whh, sw,
                                        W0b, W123b, Wcb, bp, swp);
  init_kernel<<<(CELLS * HID) / 256, 256, 0, stream>>>(q, embed, xb, h);

  // dst-sort both edge types (counts+fill zeroed in ONE memset)
  hipMemsetAsync(counts, 0, (size_t)4 * CELLS * 4, stream);
  hist_kernel<<<(2 * NE + 255) / 256, 256, 0, stream>>>(edst, counts);
  scan1_kernel<<<192, 1024, 0, stream>>>(counts, Sarr, btot);
  scan23_kernel<<<192, 1024, 0, stream>>>(btot, Sarr);
  scatter_kernel<<<(2 * NE + 255) / 256, 256, 0, stream>>>(esrc, edst, Sarr, fill, ssrc, sdst);

  // m zeroing hoisted out of the step loop: every dst with >=1 edge gets its full row
  // rewritten each step (interior flush or fixup); zero-degree rows stay zero. side_dst
  // values are step-invariant (same sorted graph), so one 0xFF fill suffices.
  hipMemsetAsync(m0, 0, (size_t)2 * CELLS * HID * 2, stream);        // m0+m1 (bf16)
  hipMemsetAsync(side_dst, 0xFF, (size_t)2 * NWIN * 2 * 4, stream);  // dst = -1

  for (int step = 0; step < NSTEPS; ++step) {
    msg_kernel<<<dim3((NE + 511) / 512, 2), 512, 0, stream>>>(h, ssrc, sdst, Sarr,
                                                              W0b, W123b, bp,
                                                              m0, m1, side_dst, side_part);
    fixup_kernel<<<2 * NWIN, 128, 0, stream>>>(Sarr, side_dst, side_part, m0, m1);
    lstm_kernel<<<CELLS / 128, 512, 0, stream>>>(step, xb, m0, m1, h, rc, Wcb, swp,
                                                 (float*)d_out);
  }
}